// Round 3
// baseline (1426.579 us; speedup 1.0000x reference)
//
#include <hip/hip_runtime.h>

#define EMB 256
typedef unsigned short u16;
typedef __attribute__((ext_vector_type(8))) short short8v;
typedef __attribute__((ext_vector_type(4))) float f32x4;

__device__ inline u16 f2bf(float x){
  union{float f; unsigned u;} c; c.f = x;
  unsigned r = c.u + 0x7FFFu + ((c.u>>16)&1u);
  return (u16)(r>>16);
}

__device__ inline short8v pack8(float4 a, float4 b){
  short8v v;
  v[0]=(short)f2bf(a.x); v[1]=(short)f2bf(a.y); v[2]=(short)f2bf(a.z); v[3]=(short)f2bf(a.w);
  v[4]=(short)f2bf(b.x); v[5]=(short)f2bf(b.y); v[6]=(short)f2bf(b.z); v[7]=(short)f2bf(b.w);
  return v;
}

// ---------------- DDE: counts + round-1 scatter fused ----------------
__global__ void k_scatter1(const int* __restrict__ h_id, const int* __restrict__ t_id,
                           const float* __restrict__ topic,
                           float* __restrict__ cnt_f, float* __restrict__ cnt_r,
                           float* __restrict__ accf, float* __restrict__ accr, int E) {
  int e = blockIdx.x * 256 + threadIdx.x;
  if (e >= E) return;
  int h = h_id[e], t = t_id[e];
  atomicAdd(&cnt_f[t], 1.0f);
  atomicAdd(&cnt_r[h], 1.0f);
  float a0 = topic[2*h+0], a1 = topic[2*h+1];
  if (a0 != 0.f) atomicAdd(&accf[2*t+0], a0);
  if (a1 != 0.f) atomicAdd(&accf[2*t+1], a1);
  float c0 = topic[2*t+0], c1 = topic[2*t+1];
  if (c0 != 0.f) atomicAdd(&accr[2*h+0], c0);
  if (c1 != 0.f) atomicAdd(&accr[2*h+1], c1);
}

__global__ void k_div1(const float* __restrict__ topic,
                       const float* __restrict__ cnt_f, const float* __restrict__ cnt_r,
                       const float* __restrict__ accf, const float* __restrict__ accr,
                       float* __restrict__ pos, int N) {
  int n = blockIdx.x * 256 + threadIdx.x;
  if (n >= N) return;
  float cf = fmaxf(cnt_f[n], 1.0f), cr = fmaxf(cnt_r[n], 1.0f);
  pos[10*n+0] = topic[2*n+0];
  pos[10*n+1] = topic[2*n+1];
  pos[10*n+2] = accf[2*n+0] / cf;
  pos[10*n+3] = accf[2*n+1] / cf;
  pos[10*n+6] = accr[2*n+0] / cr;
  pos[10*n+7] = accr[2*n+1] / cr;
}

__global__ void k_scatter2(const int* __restrict__ h_id, const int* __restrict__ t_id,
                           const float* __restrict__ pos,
                           float* __restrict__ accf, float* __restrict__ accr, int E) {
  int e = blockIdx.x * 256 + threadIdx.x;
  if (e >= E) return;
  int h = h_id[e], t = t_id[e];
  float a0 = pos[10*h+2], a1 = pos[10*h+3];
  if (a0 != 0.f) atomicAdd(&accf[2*t+0], a0);
  if (a1 != 0.f) atomicAdd(&accf[2*t+1], a1);
  float c0 = pos[10*t+6], c1 = pos[10*t+7];
  if (c0 != 0.f) atomicAdd(&accr[2*h+0], c0);
  if (c1 != 0.f) atomicAdd(&accr[2*h+1], c1);
}

__global__ void k_div2(const float* __restrict__ cnt_f, const float* __restrict__ cnt_r,
                       const float* __restrict__ accf, const float* __restrict__ accr,
                       float* __restrict__ pos, int N) {
  int n = blockIdx.x * 256 + threadIdx.x;
  if (n >= N) return;
  float cf = fmaxf(cnt_f[n], 1.0f), cr = fmaxf(cnt_r[n], 1.0f);
  pos[10*n+4] = accf[2*n+0] / cf;
  pos[10*n+5] = accf[2*n+1] / cf;
  pos[10*n+8] = accr[2*n+0] / cr;
  pos[10*n+9] = accr[2*n+1] / cr;
}

// ---------------- gate softmax + qpart = b1 + q @ W1[:256,:] ----------------
__global__ void k_gate(const float* __restrict__ q, const float* __restrict__ Wg,
                       const float* __restrict__ bg, const float* __restrict__ W1,
                       const float* __restrict__ b1, float* __restrict__ gateq) {
  __shared__ float qs[256];
  __shared__ float z[3];
  int t = threadIdx.x;
  qs[t] = q[t];
  __syncthreads();
  if (t < 3) {
    float s = bg[t];
    for (int k = 0; k < 256; ++k) s += qs[k] * Wg[k*3 + t];
    z[t] = s;
  }
  __syncthreads();
  if (t == 0) {
    float m = fmaxf(z[0], fmaxf(z[1], z[2]));
    float e0 = expf(z[0]-m), e1 = expf(z[1]-m), e2 = expf(z[2]-m);
    float s = e0 + e1 + e2;
    gateq[0] = e0/s; gateq[1] = e1/s; gateq[2] = e2/s; gateq[3] = 0.f;
  }
  float a = b1[t];
  for (int k = 0; k < 256; ++k) a += qs[k] * W1[k*256 + t];
  gateq[4 + t] = a;
}

// ---------------- weight transform: MFMA B-fragment layout, bf16 ----------------
// 35 kt-chunks of K=32: [0..15]=W_nb(512), [16]=W_pos(20,zero-pad),
// [17..26]=W_str(320), [27..34]=W1[256:512]. Frag order: ((kt*16+nt)*64+lane)*8.
__global__ void k_wtrans(const float* __restrict__ Wnb, const float* __restrict__ Wpos,
                         const float* __restrict__ Wstr, const float* __restrict__ W1,
                         u16* __restrict__ WB) {
  int gid = blockIdx.x * 256 + threadIdx.x;
  if (gid >= 35*16*64) return;
  int lane = gid & 63;
  int nt   = (gid >> 6) & 15;
  int kt   = gid >> 10;
  const float* src; int kbase, klim;
  if (kt < 16)      { src = Wnb;               kbase = kt*32;      klim = 512; }
  else if (kt==16)  { src = Wpos;              kbase = 0;          klim = 20;  }
  else if (kt < 27) { src = Wstr;              kbase = (kt-17)*32; klim = 320; }
  else              { src = W1 + 256*256;      kbase = (kt-27)*32; klim = 256; }
  int n  = nt*16 + (lane & 15);
  int k0 = kbase + (lane >> 4) * 8;
  short8v v;
  #pragma unroll
  for (int j = 0; j < 8; ++j) {
    int k = k0 + j;
    v[j] = (k < klim) ? (short)f2bf(src[(size_t)k*256 + n]) : (short)0;
  }
  *(short8v*)(WB + (size_t)gid * 8) = v;
}

// ---------------- fused MFMA main kernel: 128 edges/block, 8 waves ----------------
// Fragment-ordered LDS everywhere: chunk buffer slot = mt*64 + lane.
__global__ __launch_bounds__(512) void k_main(
    const int* __restrict__ h_id, const int* __restrict__ r_id, const int* __restrict__ t_id,
    const float* __restrict__ ent, const float* __restrict__ ntx,
    const float* __restrict__ rel,
    const int* __restrict__ mids, const float* __restrict__ mwts,
    const float* __restrict__ motif,
    const float* __restrict__ b_nb, const float* __restrict__ b_pos, const float* __restrict__ b_str,
    const float* __restrict__ W2, const float* __restrict__ b2,
    const float* __restrict__ pos, const float* __restrict__ gateq,
    const u16* __restrict__ WBg,
    float* __restrict__ out, int E, int NT)
{
  __shared__ __align__(16) u16 XA[2][4096];   // X chunk dbuf: 128 rows x 32 K (frag order), 8 KB each
  __shared__ __align__(16) u16 Bb[2][8192];   // B chunk dbuf: 16 nt x 64 lanes x 8 (frag order), 16 KB each
  __shared__ __align__(16) u16 FT[32768];     // fused [128][256] bf16 frag order, 64 KB
  __shared__ int hids[128], tids[128], rids[128];
  __shared__ float oacc[128];

  const int t  = threadIdx.x;
  const int w  = t >> 6, l = t & 63;
  const int Mw = w >> 2, Nw = w & 3;
  const int lr = l & 15, lg = l >> 4;
  const int rowbase = Mw * 64, colbase = Nw * 64;
  const int be = blockIdx.x * 128;
  const int sr = (t >> 6) * 16 + lr;   // staging row (0..127)
  const int sko = lg * 8;              // staging k-offset within chunk

  if (t < 128) {
    int e = be + t; if (e >= E) e = E - 1;
    hids[t] = h_id[e]; tids[t] = t_id[e]; rids[t] = r_id[e];
    oacc[t] = 0.f;
  }
  __syncthreads();

  const float g0 = gateq[0], g1 = gateq[1], g2 = gateq[2];

  f32x4 acc[4][4];
  float fused[4][4][4];

  auto zacc = [&]() {
    #pragma unroll
    for (int m = 0; m < 4; ++m)
      #pragma unroll
      for (int n = 0; n < 4; ++n)
        acc[m][n] = (f32x4){0.f, 0.f, 0.f, 0.f};
  };

  auto mfma16 = [&](int pb) {
    short8v bfr[4], af[4];
    #pragma unroll
    for (int n = 0; n < 4; ++n)
      bfr[n] = *(const short8v*)&Bb[pb][((Nw*4 + n)*64 + l) * 8];
    #pragma unroll
    for (int m = 0; m < 4; ++m)
      af[m] = *(const short8v*)&XA[pb][((Mw*4 + m)*64 + l) * 8];
    #pragma unroll
    for (int m = 0; m < 4; ++m)
      #pragma unroll
      for (int n = 0; n < 4; ++n)
        acc[m][n] = __builtin_amdgcn_mfma_f32_16x16x32_bf16(af[m], bfr[n], acc[m][n], 0, 0, 0);
  };

  auto combine = [&](const float* bias, float g, bool first) {
    #pragma unroll
    for (int n = 0; n < 4; ++n) {
      float bv = bias[colbase + n*16 + lr];
      #pragma unroll
      for (int m = 0; m < 4; ++m)
        #pragma unroll
        for (int r2 = 0; r2 < 4; ++r2) {
          float val = fmaxf(acc[m][n][r2] + bv, 0.f) * g;
          if (first) fused[m][n][r2] = val; else fused[m][n][r2] += val;
        }
    }
  };

  // simple-gather X source for chunk c (ent rows for c<16, rel rows for 17..24)
  auto xsrc = [&](int c) -> const float* {
    if (c < 16) {
      int id = (c < 8) ? hids[sr] : tids[sr];
      return ((id < NT) ? ent + (size_t)id * EMB : ntx) + (c & 7) * 32 + sko;
    }
    return rel + (size_t)rids[sr] * EMB + (c - 17) * 32 + sko;
  };

  // special chunk staging (pos / motif), compute + write directly
  auto stage_special = [&](int c, int buf) {
    if (c == 16) {
      float vals[8];
      #pragma unroll
      for (int j = 0; j < 8; ++j) {
        int k = sko + j;
        vals[j] = (k < 10) ? pos[(size_t)hids[sr]*10 + k]
                : (k < 20) ? pos[(size_t)tids[sr]*10 + (k - 10)] : 0.f;
      }
      short8v v;
      #pragma unroll
      for (int j = 0; j < 8; ++j) v[j] = (short)f2bf(vals[j]);
      *(short8v*)&XA[buf][t * 8] = v;
    } else {  // c == 25 or 26: motif weighted sum, dims d0..d0+8
      int d0 = (c - 25) * 32 + sko;
      int e = be + sr; if (e >= E) e = E - 1;
      float s[8] = {0,0,0,0,0,0,0,0};
      #pragma unroll
      for (int j = 0; j < 8; ++j) {
        int id = mids[(size_t)e*8 + j];
        float wv = mwts[(size_t)e*8 + j];
        if (id != 0) {
          const float* mr = motif + (size_t)id*64 + d0;
          #pragma unroll
          for (int i = 0; i < 8; ++i) s[i] = fmaf(mr[i], wv, s[i]);
        }
      }
      short8v v;
      #pragma unroll
      for (int i = 0; i < 8; ++i) v[i] = (short)f2bf(s[i]);
      *(short8v*)&XA[buf][t * 8] = v;
    }
  };

  zacc();

  // ===== prologue: stage chunk 0 (ch1-h, K 0..31) + B chunk 0 =====
  {
    const float* src = xsrc(0);
    float4 x0 = *(const float4*)src, x1 = *(const float4*)(src + 4);
    const uint4* g = (const uint4*)WBg;
    uint4 q0 = g[t*2], q1 = g[t*2 + 1];
    *(short8v*)&XA[0][t * 8] = pack8(x0, x1);
    *(uint4*)&Bb[0][t*16] = q0; *(uint4*)&Bb[0][t*16 + 8] = q1;
  }
  __syncthreads();

  // ===== main chunk loop: c = 0..26 (ch1: 0-15, ch2: 16, ch3: 17-26) =====
  for (int c = 0; c < 27; ++c) {
    int pb = c & 1, nb = pb ^ 1;
    int nxt = c + 1;
    bool hn = (nxt < 27);
    bool simp = hn && ((nxt < 16) || (nxt >= 17 && nxt < 25));
    uint4 q0, q1; float4 x0, x1;
    if (hn) {  // issue next-chunk global loads early
      const uint4* g = (const uint4*)(WBg + (size_t)nxt * 8192);
      q0 = g[t*2]; q1 = g[t*2 + 1];
      if (simp) {
        const float* src = xsrc(nxt);
        x0 = *(const float4*)src; x1 = *(const float4*)(src + 4);
      }
    }
    mfma16(pb);
    if (c == 15) { combine(b_nb,  g0, true);  zacc(); }
    if (c == 16) { combine(b_pos, g1, false); zacc(); }
    if (hn) {    // write next chunk (latency hidden under MFMA)
      *(uint4*)&Bb[nb][t*16] = q0; *(uint4*)&Bb[nb][t*16 + 8] = q1;
      if (simp) *(short8v*)&XA[nb][t * 8] = pack8(x0, x1);
      else stage_special(nxt, nb);
    }
    __syncthreads();
  }
  // issue layer-1 B chunk 27 loads before the FT scatter
  uint4 q0, q1;
  {
    const uint4* g = (const uint4*)(WBg + (size_t)27 * 8192);
    q0 = g[t*2]; q1 = g[t*2 + 1];
  }
  combine(b_str, g2, false);

  // ===== write fused -> FT (bf16, frag order) =====
  #pragma unroll
  for (int m = 0; m < 4; ++m) {
    int mt = Mw*4 + m;
    #pragma unroll
    for (int n = 0; n < 4; ++n) {
      int kcol = colbase + n*16 + lr;
      int base = ((mt*8 + (kcol >> 5))*64 + ((kcol >> 3) & 3)*16)*8 + (kcol & 7);
      #pragma unroll
      for (int r2 = 0; r2 < 4; ++r2)
        FT[base + (lg*4 + r2)*8] = f2bf(fused[m][n][r2]);
    }
  }
  *(uint4*)&Bb[0][t*16] = q0; *(uint4*)&Bb[0][t*16 + 8] = q1;

  // init acc with qpart (b1 + q@W1_top), broadcast along rows
  #pragma unroll
  for (int n = 0; n < 4; ++n) {
    float qv = gateq[4 + colbase + n*16 + lr];
    #pragma unroll
    for (int m = 0; m < 4; ++m) acc[m][n] = (f32x4){qv, qv, qv, qv};
  }
  __syncthreads();

  // ===== layer 1: 8 chunks, A from FT, B = WB kt 27..34 =====
  for (int c2 = 0; c2 < 8; ++c2) {
    int pb = c2 & 1;
    bool hn = (c2 < 7);
    uint4 r0, r1;
    if (hn) {
      const uint4* g = (const uint4*)(WBg + (size_t)(28 + c2) * 8192);
      r0 = g[t*2]; r1 = g[t*2 + 1];
    }
    short8v bfr[4], af[4];
    #pragma unroll
    for (int n = 0; n < 4; ++n)
      bfr[n] = *(const short8v*)&Bb[pb][((Nw*4 + n)*64 + l) * 8];
    #pragma unroll
    for (int m = 0; m < 4; ++m)
      af[m] = *(const short8v*)&FT[(((Mw*4 + m)*8 + c2)*64 + l) * 8];
    #pragma unroll
    for (int m = 0; m < 4; ++m)
      #pragma unroll
      for (int n = 0; n < 4; ++n)
        acc[m][n] = __builtin_amdgcn_mfma_f32_16x16x32_bf16(af[m], bfr[n], acc[m][n], 0, 0, 0);
    if (hn) { *(uint4*)&Bb[pb^1][t*16] = r0; *(uint4*)&Bb[pb^1][t*16 + 8] = r1; }
    __syncthreads();
  }

  // ===== layer 2: out = relu(act) @ W2 + b2 =====
  {
    float w2v[4];
    #pragma unroll
    for (int n = 0; n < 4; ++n) w2v[n] = W2[colbase + n*16 + lr];
    #pragma unroll
    for (int m = 0; m < 4; ++m)
      #pragma unroll
      for (int r2 = 0; r2 < 4; ++r2) {
        float p = 0.f;
        #pragma unroll
        for (int n = 0; n < 4; ++n) p = fmaf(fmaxf(acc[m][n][r2], 0.f), w2v[n], p);
        p += __shfl_xor(p, 1); p += __shfl_xor(p, 2);
        p += __shfl_xor(p, 4); p += __shfl_xor(p, 8);
        if (lr == 0) atomicAdd(&oacc[rowbase + m*16 + lg*4 + r2], p);
      }
  }
  __syncthreads();
  if (t < 128) {
    int e = be + t;
    if (e < E) out[e] = oacc[t] + b2[0];
  }
}

extern "C" void kernel_launch(void* const* d_in, const int* in_sizes, int n_in,
                              void* d_out, int out_size, void* d_ws, size_t ws_size,
                              hipStream_t stream) {
  const int*   h_id  = (const int*)  d_in[0];
  const int*   r_id  = (const int*)  d_in[1];
  const int*   t_id  = (const int*)  d_in[2];
  const float* q     = (const float*)d_in[3];
  const float* ent   = (const float*)d_in[4];
  const float* rel   = (const float*)d_in[6];
  const float* topic = (const float*)d_in[7];
  const int*   mids  = (const int*)  d_in[8];
  const float* mwts  = (const float*)d_in[9];
  const float* ntx   = (const float*)d_in[10];
  const float* motif = (const float*)d_in[11];
  const float* W_nb  = (const float*)d_in[12];
  const float* b_nb  = (const float*)d_in[13];
  const float* W_pos = (const float*)d_in[14];
  const float* b_pos = (const float*)d_in[15];
  const float* W_str = (const float*)d_in[16];
  const float* b_str = (const float*)d_in[17];
  const float* W_g   = (const float*)d_in[18];
  const float* b_g   = (const float*)d_in[19];
  const float* W1    = (const float*)d_in[20];
  const float* b1    = (const float*)d_in[21];
  const float* W2    = (const float*)d_in[22];
  const float* b2    = (const float*)d_in[23];
  float* out = (float*)d_out;

  const int E  = in_sizes[0];
  const int NT = in_sizes[4] / EMB;   // 80000 text entities
  const int N  = in_sizes[7] / 2;     // 100000 total nodes

  float* ws    = (float*)d_ws;
  float* cnt_f = ws;
  float* cnt_r = ws + (size_t)N;
  float* a1f   = ws + (size_t)2*N;
  float* a1r   = ws + (size_t)4*N;
  float* a2f   = ws + (size_t)6*N;
  float* a2r   = ws + (size_t)8*N;
  float* pos   = ws + (size_t)10*N;   // N x 10
  float* gateq = ws + (size_t)20*N;   // [g0,g1,g2,pad, qpart(256)]
  u16*   WBg   = (u16*)(ws + (size_t)20*N + 512);  // 35 chunks x 16KB bf16 frags

  hipMemsetAsync(d_ws, 0, (size_t)10 * N * sizeof(float), stream);

  int gE = (E + 255) / 256, gN = (N + 255) / 256;
  k_scatter1<<<gE, 256, 0, stream>>>(h_id, t_id, topic, cnt_f, cnt_r, a1f, a1r, E);
  k_div1    <<<gN, 256, 0, stream>>>(topic, cnt_f, cnt_r, a1f, a1r, pos, N);
  k_scatter2<<<gE, 256, 0, stream>>>(h_id, t_id, pos, a2f, a2r, E);
  k_div2    <<<gN, 256, 0, stream>>>(cnt_f, cnt_r, a2f, a2r, pos, N);
  k_gate    <<<1, 256, 0, stream>>>(q, W_g, b_g, W1, b1, gateq);
  k_wtrans  <<<140, 256, 0, stream>>>(W_nb, W_pos, W_str, W1, (u16*)WBg);

  int gM = (E + 127) / 128;
  k_main<<<gM, 512, 0, stream>>>(h_id, r_id, t_id, ent, ntx, rel, mids, mwts, motif,
                                 b_nb, b_pos, b_str, W2, b2,
                                 pos, gateq, WBg, out, E, NT);
}

// Round 4
// 582.572 us; speedup vs baseline: 2.4488x; 2.4488x over previous
//
#include <hip/hip_runtime.h>

#define EMB 256
typedef unsigned short u16;
typedef __attribute__((ext_vector_type(8))) short short8v;
typedef __attribute__((ext_vector_type(4))) short short4v;
typedef __attribute__((ext_vector_type(4))) float f32x4;

__device__ inline u16 f2bf(float x){
  union{float f; unsigned u;} c; c.f = x;
  unsigned r = c.u + 0x7FFFu + ((c.u>>16)&1u);
  return (u16)(r>>16);
}
__device__ inline float bf2f(u16 h){
  union{unsigned u; float f;} c; c.u = ((unsigned)h) << 16; return c.f;
}
__device__ inline short8v pack8(float4 a, float4 b){
  short8v v;
  v[0]=(short)f2bf(a.x); v[1]=(short)f2bf(a.y); v[2]=(short)f2bf(a.z); v[3]=(short)f2bf(a.w);
  v[4]=(short)f2bf(b.x); v[5]=(short)f2bf(b.y); v[6]=(short)f2bf(b.z); v[7]=(short)f2bf(b.w);
  return v;
}

// ---------------- DDE: counts + round-1 scatter fused ----------------
__global__ void k_scatter1(const int* __restrict__ h_id, const int* __restrict__ t_id,
                           const float* __restrict__ topic,
                           float* __restrict__ cnt_f, float* __restrict__ cnt_r,
                           float* __restrict__ accf, float* __restrict__ accr, int E) {
  int e = blockIdx.x * 256 + threadIdx.x;
  if (e >= E) return;
  int h = h_id[e], t = t_id[e];
  atomicAdd(&cnt_f[t], 1.0f);
  atomicAdd(&cnt_r[h], 1.0f);
  float a0 = topic[2*h+0], a1 = topic[2*h+1];
  if (a0 != 0.f) atomicAdd(&accf[2*t+0], a0);
  if (a1 != 0.f) atomicAdd(&accf[2*t+1], a1);
  float c0 = topic[2*t+0], c1 = topic[2*t+1];
  if (c0 != 0.f) atomicAdd(&accr[2*h+0], c0);
  if (c1 != 0.f) atomicAdd(&accr[2*h+1], c1);
}

__global__ void k_div1(const float* __restrict__ topic,
                       const float* __restrict__ cnt_f, const float* __restrict__ cnt_r,
                       const float* __restrict__ accf, const float* __restrict__ accr,
                       float* __restrict__ pos, int N) {
  int n = blockIdx.x * 256 + threadIdx.x;
  if (n >= N) return;
  float cf = fmaxf(cnt_f[n], 1.0f), cr = fmaxf(cnt_r[n], 1.0f);
  pos[10*n+0] = topic[2*n+0];
  pos[10*n+1] = topic[2*n+1];
  pos[10*n+2] = accf[2*n+0] / cf;
  pos[10*n+3] = accf[2*n+1] / cf;
  pos[10*n+6] = accr[2*n+0] / cr;
  pos[10*n+7] = accr[2*n+1] / cr;
}

__global__ void k_scatter2(const int* __restrict__ h_id, const int* __restrict__ t_id,
                           const float* __restrict__ pos,
                           float* __restrict__ accf, float* __restrict__ accr, int E) {
  int e = blockIdx.x * 256 + threadIdx.x;
  if (e >= E) return;
  int h = h_id[e], t = t_id[e];
  float a0 = pos[10*h+2], a1 = pos[10*h+3];
  if (a0 != 0.f) atomicAdd(&accf[2*t+0], a0);
  if (a1 != 0.f) atomicAdd(&accf[2*t+1], a1);
  float c0 = pos[10*t+6], c1 = pos[10*t+7];
  if (c0 != 0.f) atomicAdd(&accr[2*h+0], c0);
  if (c1 != 0.f) atomicAdd(&accr[2*h+1], c1);
}

__global__ void k_div2(const float* __restrict__ cnt_f, const float* __restrict__ cnt_r,
                       const float* __restrict__ accf, const float* __restrict__ accr,
                       float* __restrict__ pos, int N) {
  int n = blockIdx.x * 256 + threadIdx.x;
  if (n >= N) return;
  float cf = fmaxf(cnt_f[n], 1.0f), cr = fmaxf(cnt_r[n], 1.0f);
  pos[10*n+4] = accf[2*n+0] / cf;
  pos[10*n+5] = accf[2*n+1] / cf;
  pos[10*n+8] = accr[2*n+0] / cr;
  pos[10*n+9] = accr[2*n+1] / cr;
}

// ---------------- gate softmax + qpart = b1 + q @ W1[:256,:] ----------------
__global__ void k_gate(const float* __restrict__ q, const float* __restrict__ Wg,
                       const float* __restrict__ bg, const float* __restrict__ W1,
                       const float* __restrict__ b1, float* __restrict__ gateq) {
  __shared__ float qs[256];
  __shared__ float z[3];
  int t = threadIdx.x;
  qs[t] = q[t];
  __syncthreads();
  if (t < 3) {
    float s = bg[t];
    for (int k = 0; k < 256; ++k) s += qs[k] * Wg[k*3 + t];
    z[t] = s;
  }
  __syncthreads();
  if (t == 0) {
    float m = fmaxf(z[0], fmaxf(z[1], z[2]));
    float e0 = expf(z[0]-m), e1 = expf(z[1]-m), e2 = expf(z[2]-m);
    float s = e0 + e1 + e2;
    gateq[0] = e0/s; gateq[1] = e1/s; gateq[2] = e2/s; gateq[3] = 0.f;
  }
  float a = b1[t];
  for (int k = 0; k < 256; ++k) a += qs[k] * W1[k*256 + t];
  gateq[4 + t] = a;
}

// ---------------- weight transform: MFMA A-fragment layout, bf16 ----------------
// 35 kt-chunks of K=32: [0..15]=W_nb(512), [16]=W_pos(20,zero-pad),
// [17..26]=W_str(320), [27..34]=W1[256:512].
// A-frag: lane l <-> (feature ft*16+(l&15), k = (l>>4)*8+j). Slot ((kt*16+ft)*64+l)*8+j.
__global__ void k_wtrans(const float* __restrict__ Wnb, const float* __restrict__ Wpos,
                         const float* __restrict__ Wstr, const float* __restrict__ W1,
                         u16* __restrict__ WB) {
  int gid = blockIdx.x * 256 + threadIdx.x;
  if (gid >= 35*16*64) return;
  int lane = gid & 63;
  int ft   = (gid >> 6) & 15;
  int kt   = gid >> 10;
  const float* src; int kbase, klim;
  if (kt < 16)      { src = Wnb;               kbase = kt*32;      klim = 512; }
  else if (kt==16)  { src = Wpos;              kbase = 0;          klim = 20;  }
  else if (kt < 27) { src = Wstr;              kbase = (kt-17)*32; klim = 320; }
  else              { src = W1 + 256*256;      kbase = (kt-27)*32; klim = 256; }
  int n  = ft*16 + (lane & 15);
  int k0 = kbase + (lane >> 4) * 8;
  short8v v;
  #pragma unroll
  for (int j = 0; j < 8; ++j) {
    int k = k0 + j;
    v[j] = (k < klim) ? (short)f2bf(src[(size_t)k*256 + n]) : (short)0;
  }
  *(short8v*)(WB + (size_t)gid * 8) = v;
}

// ---------------- fused MFMA main kernel: 128 edges/block, 8 waves ----------------
// Operand-swapped: D[feature][edge] = W(A) x X^T(B). 8 waves = 4(M=feat) x 2(N=edge).
__global__ __launch_bounds__(512) __attribute__((amdgpu_waves_per_eu(2)))
void k_main(
    const int* __restrict__ h_id, const int* __restrict__ r_id, const int* __restrict__ t_id,
    const float* __restrict__ ent, const float* __restrict__ ntx,
    const float* __restrict__ rel,
    const int* __restrict__ mids, const float* __restrict__ mwts,
    const float* __restrict__ motif,
    const float* __restrict__ b_nb, const float* __restrict__ b_pos, const float* __restrict__ b_str,
    const float* __restrict__ W2, const float* __restrict__ b2,
    const float* __restrict__ pos, const float* __restrict__ gateq,
    const u16* __restrict__ WBg,
    float* __restrict__ out, int E, int NT)
{
  __shared__ __align__(16) u16 XBs[4*8*64*8];    // X part: 4 chunks x 8 edge-tiles (32 KB)
  __shared__ __align__(16) u16 WA[2][16*64*8];   // W chunk dbuf: 16 feat-tiles (16 KB each)
  __shared__ __align__(16) u16 FT2[8*8*64*8];    // fused [k=256][edge=128] frag order (64 KB)
  __shared__ float woacc[4][128];

  const int t  = threadIdx.x;
  const int wv = t >> 6, l = t & 63;
  const int Mw = wv >> 1, Nw = wv & 1;           // 4 x 2 wave grid
  const int lr = l & 15, lg = l >> 4;
  const int be = blockIdx.x * 128;
  const int sr = wv * 16 + lr;                   // staging edge row 0..127
  const int sko = lg * 8;                        // staging k offset

  // per-thread edge ids (row sr)
  int e_r = be + sr; if (e_r >= E) e_r = E - 1;
  const int hid = h_id[e_r], tid = t_id[e_r], rid = r_id[e_r];
  const float* hrow = (hid < NT) ? (ent + (size_t)hid * EMB) : ntx;
  const float* trow = (tid < NT) ? (ent + (size_t)tid * EMB) : ntx;
  const float* rrow = rel + (size_t)rid * EMB;

  const float g0 = gateq[0], g1 = gateq[1], g2 = gateq[2];

  f32x4 acc[4][4];
  short8v xp[4];     // X prefetch (next part)
  uint4 wq0, wq1;    // W prefetch (next chunk)

  auto zacc = [&]() {
    #pragma unroll
    for (int m = 0; m < 4; ++m)
      #pragma unroll
      for (int n = 0; n < 4; ++n)
        acc[m][n] = (f32x4){0.f, 0.f, 0.f, 0.f};
  };

  auto wprefetch = [&](int kt) {
    const uint4* g = (const uint4*)(WBg + (size_t)kt * 8192);
    wq0 = g[t*2]; wq1 = g[t*2 + 1];
  };
  auto wwrite = [&](int kt) {
    uint4* d = (uint4*)&WA[kt & 1][0];
    d[t*2] = wq0; d[t*2 + 1] = wq1;
  };

  auto xprefetch = [&](const float* rowptr, int ncc) {
    #pragma unroll
    for (int cc = 0; cc < 4; ++cc) if (cc < ncc) {
      float4 a = *(const float4*)(rowptr + cc*32 + sko);
      float4 b = *(const float4*)(rowptr + cc*32 + sko + 4);
      xp[cc] = pack8(a, b);
    }
  };
  auto xwrite = [&](int ncc) {
    #pragma unroll
    for (int cc = 0; cc < 4; ++cc) if (cc < ncc)
      *(short8v*)&XBs[((cc*8 + wv)*64 + l)*8] = xp[cc];
  };

  auto chunk = [&](int kt, const u16* xbase, int cc) {
    short8v bfr[4], af[4];
    const u16* wb = WA[kt & 1];
    #pragma unroll
    for (int n = 0; n < 4; ++n)
      bfr[n] = *(const short8v*)&xbase[((cc*8 + Nw*4 + n)*64 + l)*8];
    #pragma unroll
    for (int m = 0; m < 4; ++m)
      af[m] = *(const short8v*)&wb[((Mw*4 + m)*64 + l)*8];
    #pragma unroll
    for (int m = 0; m < 4; ++m)
      #pragma unroll
      for (int n = 0; n < 4; ++n)
        acc[m][n] = __builtin_amdgcn_mfma_f32_16x16x32_bf16(af[m], bfr[n], acc[m][n], 0, 0, 0);
  };

  auto part = [&](int ktbase, int nc, const u16* xbase) {
    for (int i = 0; i < nc; ++i) {
      int kt = ktbase + i;
      if (kt < 34) wprefetch(kt + 1);
      chunk(kt, xbase, i);
      if (kt < 34) wwrite(kt + 1);
      __syncthreads();
    }
  };

  // channel result -> FT2 (bf16 frag order), RMW accumulate
  auto combine = [&](const float* bias, float g, bool first) {
    #pragma unroll
    for (int m = 0; m < 4; ++m) {
      int f0 = Mw*64 + m*16 + lg*4;
      float bv0 = bias[f0+0], bv1 = bias[f0+1], bv2 = bias[f0+2], bv3 = bias[f0+3];
      int kc  = Mw*2 + ((m*4 + lg) >> 3);
      int lg2 = (m*2 + (lg >> 1)) & 3;
      #pragma unroll
      for (int n = 0; n < 4; ++n) {
        int nt = Nw*4 + n;
        int idx = ((kc*8 + nt)*64 + lg2*16 + lr)*8 + (lg & 1)*4;
        float v0 = g * fmaxf(acc[m][n][0] + bv0, 0.f);
        float v1 = g * fmaxf(acc[m][n][1] + bv1, 0.f);
        float v2 = g * fmaxf(acc[m][n][2] + bv2, 0.f);
        float v3 = g * fmaxf(acc[m][n][3] + bv3, 0.f);
        if (!first) {
          short4v o = *(short4v*)&FT2[idx];
          v0 += bf2f((u16)o[0]); v1 += bf2f((u16)o[1]);
          v2 += bf2f((u16)o[2]); v3 += bf2f((u16)o[3]);
        }
        short4v w;
        w[0] = (short)f2bf(v0); w[1] = (short)f2bf(v1);
        w[2] = (short)f2bf(v2); w[3] = (short)f2bf(v3);
        *(short4v*)&FT2[idx] = w;
      }
    }
  };

  // ===== prologue =====
  zacc();
  xprefetch(hrow, 4);
  wprefetch(0);
  xwrite(4);
  wwrite(0);
  xprefetch(hrow + 128, 4);     // P1
  __syncthreads();

  // ===== channel 1: h rows (P0,P1) + t rows (P2,P3), kt 0..15 =====
  part(0, 4, XBs);
  xwrite(4); xprefetch(trow, 4); __syncthreads();
  part(4, 4, XBs);
  xwrite(4); xprefetch(trow + 128, 4); __syncthreads();
  part(8, 4, XBs);
  xwrite(4); xprefetch(rrow, 4);  // prefetch rel-lo early (held across P3, P4)
  __syncthreads();
  part(12, 4, XBs);
  combine(b_nb, g0, true);
  zacc();
  // stage pos chunk inline (cc=0)
  {
    float vals[8];
    #pragma unroll
    for (int j = 0; j < 8; ++j) {
      int k = sko + j;
      vals[j] = (k < 10) ? pos[(size_t)hid*10 + k]
              : (k < 20) ? pos[(size_t)tid*10 + (k - 10)] : 0.f;
    }
    short8v v;
    #pragma unroll
    for (int j = 0; j < 8; ++j) v[j] = (short)f2bf(vals[j]);
    *(short8v*)&XBs[((0*8 + wv)*64 + l)*8] = v;
  }
  __syncthreads();

  // ===== channel 2: pos, kt 16 =====
  part(16, 1, XBs);
  combine(b_pos, g1, false);
  zacc();
  xwrite(4); xprefetch(rrow + 128, 4); __syncthreads();

  // ===== channel 3: rel (P5,P6) + motif (P7), kt 17..26 =====
  part(17, 4, XBs);
  xwrite(4); __syncthreads();
  part(21, 4, XBs);
  // stage motif chunks inline (cc=0,1)
  {
    int ids8[8]; float ws8[8];
    #pragma unroll
    for (int j = 0; j < 8; ++j) {
      ids8[j] = mids[(size_t)e_r*8 + j];
      ws8[j]  = mwts[(size_t)e_r*8 + j];
    }
    #pragma unroll
    for (int cc = 0; cc < 2; ++cc) {
      int d0 = cc*32 + sko;
      float s[8] = {0,0,0,0,0,0,0,0};
      #pragma unroll
      for (int j = 0; j < 8; ++j) {
        if (ids8[j] != 0) {
          const float* mr = motif + (size_t)ids8[j]*64 + d0;
          #pragma unroll
          for (int i = 0; i < 8; ++i) s[i] = fmaf(mr[i], ws8[j], s[i]);
        }
      }
      short8v v;
      #pragma unroll
      for (int i = 0; i < 8; ++i) v[i] = (short)f2bf(s[i]);
      *(short8v*)&XBs[((cc*8 + wv)*64 + l)*8] = v;
    }
  }
  __syncthreads();
  part(25, 2, XBs);
  combine(b_str, g2, false);

  // ===== layer 1: acc init = qpart (b1 + q@W1_top), B = FT2, kt 27..34 =====
  #pragma unroll
  for (int m = 0; m < 4; ++m) {
    int f0 = Mw*64 + m*16 + lg*4;
    f32x4 qv = { gateq[4+f0], gateq[5+f0], gateq[6+f0], gateq[7+f0] };
    #pragma unroll
    for (int n = 0; n < 4; ++n) acc[m][n] = qv;
  }
  __syncthreads();
  part(27, 8, FT2);

  // ===== layer 2: out = relu(act) @ W2 + b2, per-wave partials =====
  {
    float w2v[4][4];
    #pragma unroll
    for (int m = 0; m < 4; ++m) {
      int f0 = Mw*64 + m*16 + lg*4;
      #pragma unroll
      for (int r2 = 0; r2 < 4; ++r2) w2v[m][r2] = W2[f0 + r2];
    }
    #pragma unroll
    for (int n = 0; n < 4; ++n) {
      float p = 0.f;
      #pragma unroll
      for (int m = 0; m < 4; ++m)
        #pragma unroll
        for (int r2 = 0; r2 < 4; ++r2)
          p = fmaf(fmaxf(acc[m][n][r2], 0.f), w2v[m][r2], p);
      p += __shfl_xor(p, 16);
      p += __shfl_xor(p, 32);
      if (lg == 0) woacc[Mw][Nw*64 + n*16 + lr] = p;
    }
  }
  __syncthreads();
  if (t < 128) {
    int e = be + t;
    if (e < E)
      out[e] = woacc[0][t] + woacc[1][t] + woacc[2][t] + woacc[3][t] + b2[0];
  }
}

extern "C" void kernel_launch(void* const* d_in, const int* in_sizes, int n_in,
                              void* d_out, int out_size, void* d_ws, size_t ws_size,
                              hipStream_t stream) {
  const int*   h_id  = (const int*)  d_in[0];
  const int*   r_id  = (const int*)  d_in[1];
  const int*   t_id  = (const int*)  d_in[2];
  const float* q     = (const float*)d_in[3];
  const float* ent   = (const float*)d_in[4];
  const float* rel   = (const float*)d_in[6];
  const float* topic = (const float*)d_in[7];
  const int*   mids  = (const int*)  d_in[8];
  const float* mwts  = (const float*)d_in[9];
  const float* ntx   = (const float*)d_in[10];
  const float* motif = (const float*)d_in[11];
  const float* W_nb  = (const float*)d_in[12];
  const float* b_nb  = (const float*)d_in[13];
  const float* W_pos = (const float*)d_in[14];
  const float* b_pos = (const float*)d_in[15];
  const float* W_str = (const float*)d_in[16];
  const float* b_str = (const float*)d_in[17];
  const float* W_g   = (const float*)d_in[18];
  const float* b_g   = (const float*)d_in[19];
  const float* W1    = (const float*)d_in[20];
  const float* b1    = (const float*)d_in[21];
  const float* W2    = (const float*)d_in[22];
  const float* b2    = (const float*)d_in[23];
  float* out = (float*)d_out;

  const int E  = in_sizes[0];
  const int NT = in_sizes[4] / EMB;   // 80000 text entities
  const int N  = in_sizes[7] / 2;     // 100000 total nodes

  float* ws    = (float*)d_ws;
  float* cnt_f = ws;
  float* cnt_r = ws + (size_t)N;
  float* a1f   = ws + (size_t)2*N;
  float* a1r   = ws + (size_t)4*N;
  float* a2f   = ws + (size_t)6*N;
  float* a2r   = ws + (size_t)8*N;
  float* pos   = ws + (size_t)10*N;   // N x 10
  float* gateq = ws + (size_t)20*N;   // [g0,g1,g2,pad, qpart(256)]
  u16*   WBg   = (u16*)(ws + (size_t)20*N + 512);  // 35 chunks x 16KB bf16 frags

  hipMemsetAsync(d_ws, 0, (size_t)10 * N * sizeof(float), stream);

  int gE = (E + 255) / 256, gN = (N + 255) / 256;
  k_scatter1<<<gE, 256, 0, stream>>>(h_id, t_id, topic, cnt_f, cnt_r, a1f, a1r, E);
  k_div1    <<<gN, 256, 0, stream>>>(topic, cnt_f, cnt_r, a1f, a1r, pos, N);
  k_scatter2<<<gE, 256, 0, stream>>>(h_id, t_id, pos, a2f, a2r, E);
  k_div2    <<<gN, 256, 0, stream>>>(cnt_f, cnt_r, a2f, a2r, pos, N);
  k_gate    <<<1, 256, 0, stream>>>(q, W_g, b_g, W1, b1, gateq);
  k_wtrans  <<<140, 256, 0, stream>>>(W_nb, W_pos, W_str, W1, (u16*)WBg);

  int gM = (E + 127) / 128;
  k_main<<<gM, 512, 0, stream>>>(h_id, r_id, t_id, ent, ntx, rel, mids, mwts, motif,
                                 b_nb, b_pos, b_str, W2, b2,
                                 pos, gateq, WBg, out, E, NT);
}

// Round 5
// 560.403 us; speedup vs baseline: 2.5456x; 1.0396x over previous
//
#include <hip/hip_runtime.h>

#define EMB 256
typedef unsigned short u16;
typedef __attribute__((ext_vector_type(8))) short short8v;
typedef __attribute__((ext_vector_type(4))) short short4v;
typedef __attribute__((ext_vector_type(4))) float f32x4;

__device__ inline u16 f2bf(float x){
  union{float f; unsigned u;} c; c.f = x;
  unsigned r = c.u + 0x7FFFu + ((c.u>>16)&1u);
  return (u16)(r>>16);
}
__device__ inline float bf2f(u16 h){
  union{unsigned u; float f;} c; c.u = ((unsigned)h) << 16; return c.f;
}
__device__ inline short8v pack8(float4 a, float4 b){
  short8v v;
  v[0]=(short)f2bf(a.x); v[1]=(short)f2bf(a.y); v[2]=(short)f2bf(a.z); v[3]=(short)f2bf(a.w);
  v[4]=(short)f2bf(b.x); v[5]=(short)f2bf(b.y); v[6]=(short)f2bf(b.z); v[7]=(short)f2bf(b.w);
  return v;
}

// ---------------- DDE: counts + round-1 scatter fused ----------------
__global__ void k_scatter1(const int* __restrict__ h_id, const int* __restrict__ t_id,
                           const float* __restrict__ topic,
                           float* __restrict__ cnt_f, float* __restrict__ cnt_r,
                           float* __restrict__ accf, float* __restrict__ accr, int E) {
  int e = blockIdx.x * 256 + threadIdx.x;
  if (e >= E) return;
  int h = h_id[e], t = t_id[e];
  atomicAdd(&cnt_f[t], 1.0f);
  atomicAdd(&cnt_r[h], 1.0f);
  float a0 = topic[2*h+0], a1 = topic[2*h+1];
  if (a0 != 0.f) atomicAdd(&accf[2*t+0], a0);
  if (a1 != 0.f) atomicAdd(&accf[2*t+1], a1);
  float c0 = topic[2*t+0], c1 = topic[2*t+1];
  if (c0 != 0.f) atomicAdd(&accr[2*h+0], c0);
  if (c1 != 0.f) atomicAdd(&accr[2*h+1], c1);
}

__global__ void k_div1(const float* __restrict__ topic,
                       const float* __restrict__ cnt_f, const float* __restrict__ cnt_r,
                       const float* __restrict__ accf, const float* __restrict__ accr,
                       float* __restrict__ pos, int N) {
  int n = blockIdx.x * 256 + threadIdx.x;
  if (n >= N) return;
  float cf = fmaxf(cnt_f[n], 1.0f), cr = fmaxf(cnt_r[n], 1.0f);
  pos[10*n+0] = topic[2*n+0];
  pos[10*n+1] = topic[2*n+1];
  pos[10*n+2] = accf[2*n+0] / cf;
  pos[10*n+3] = accf[2*n+1] / cf;
  pos[10*n+6] = accr[2*n+0] / cr;
  pos[10*n+7] = accr[2*n+1] / cr;
}

__global__ void k_scatter2(const int* __restrict__ h_id, const int* __restrict__ t_id,
                           const float* __restrict__ pos,
                           float* __restrict__ accf, float* __restrict__ accr, int E) {
  int e = blockIdx.x * 256 + threadIdx.x;
  if (e >= E) return;
  int h = h_id[e], t = t_id[e];
  float a0 = pos[10*h+2], a1 = pos[10*h+3];
  if (a0 != 0.f) atomicAdd(&accf[2*t+0], a0);
  if (a1 != 0.f) atomicAdd(&accf[2*t+1], a1);
  float c0 = pos[10*t+6], c1 = pos[10*t+7];
  if (c0 != 0.f) atomicAdd(&accr[2*h+0], c0);
  if (c1 != 0.f) atomicAdd(&accr[2*h+1], c1);
}

__global__ void k_div2(const float* __restrict__ cnt_f, const float* __restrict__ cnt_r,
                       const float* __restrict__ accf, const float* __restrict__ accr,
                       float* __restrict__ pos, int N) {
  int n = blockIdx.x * 256 + threadIdx.x;
  if (n >= N) return;
  float cf = fmaxf(cnt_f[n], 1.0f), cr = fmaxf(cnt_r[n], 1.0f);
  pos[10*n+4] = accf[2*n+0] / cf;
  pos[10*n+5] = accf[2*n+1] / cf;
  pos[10*n+8] = accr[2*n+0] / cr;
  pos[10*n+9] = accr[2*n+1] / cr;
}

// ---------------- gate softmax + qpart = b1 + q @ W1[:256,:] ----------------
__global__ void k_gate(const float* __restrict__ q, const float* __restrict__ Wg,
                       const float* __restrict__ bg, const float* __restrict__ W1,
                       const float* __restrict__ b1, float* __restrict__ gateq) {
  __shared__ float qs[256];
  __shared__ float z[3];
  int t = threadIdx.x;
  qs[t] = q[t];
  __syncthreads();
  if (t < 3) {
    float s = bg[t];
    for (int k = 0; k < 256; ++k) s += qs[k] * Wg[k*3 + t];
    z[t] = s;
  }
  __syncthreads();
  if (t == 0) {
    float m = fmaxf(z[0], fmaxf(z[1], z[2]));
    float e0 = expf(z[0]-m), e1 = expf(z[1]-m), e2 = expf(z[2]-m);
    float s = e0 + e1 + e2;
    gateq[0] = e0/s; gateq[1] = e1/s; gateq[2] = e2/s; gateq[3] = 0.f;
  }
  float a = b1[t];
  for (int k = 0; k < 256; ++k) a += qs[k] * W1[k*256 + t];
  gateq[4 + t] = a;
}

// ---------------- weight transform: MFMA A-fragment layout, bf16 ----------------
// 35 kt-chunks of K=32: [0..15]=W_nb(512), [16]=W_pos(20,zero-pad),
// [17..26]=W_str(320), [27..34]=W1[256:512].
// A-frag: lane l <-> (feature ft*16+(l&15), k = (l>>4)*8+j). Slot ((kt*16+ft)*64+l)*8+j.
__global__ void k_wtrans(const float* __restrict__ Wnb, const float* __restrict__ Wpos,
                         const float* __restrict__ Wstr, const float* __restrict__ W1,
                         u16* __restrict__ WB) {
  int gid = blockIdx.x * 256 + threadIdx.x;
  if (gid >= 35*16*64) return;
  int lane = gid & 63;
  int ft   = (gid >> 6) & 15;
  int kt   = gid >> 10;
  const float* src; int kbase, klim;
  if (kt < 16)      { src = Wnb;               kbase = kt*32;      klim = 512; }
  else if (kt==16)  { src = Wpos;              kbase = 0;          klim = 20;  }
  else if (kt < 27) { src = Wstr;              kbase = (kt-17)*32; klim = 320; }
  else              { src = W1 + 256*256;      kbase = (kt-27)*32; klim = 256; }
  int n  = ft*16 + (lane & 15);
  int k0 = kbase + (lane >> 4) * 8;
  short8v v;
  #pragma unroll
  for (int j = 0; j < 8; ++j) {
    int k = k0 + j;
    v[j] = (k < klim) ? (short)f2bf(src[(size_t)k*256 + n]) : (short)0;
  }
  *(short8v*)(WB + (size_t)gid * 8) = v;
}

// ---------------- fused MFMA main kernel: 128 edges/block, 8 waves ----------------
// Operand-swapped: D[feature][edge] = W(A) x X^T(B). 8 waves = 4(M=feat) x 2(N=edge).
// W fragments read DIRECT from global (L2-resident WBg) — no LDS staging for W.
__global__ __launch_bounds__(512, 4) void k_main(
    const int* __restrict__ h_id, const int* __restrict__ r_id, const int* __restrict__ t_id,
    const float* __restrict__ ent, const float* __restrict__ ntx,
    const float* __restrict__ rel,
    const int* __restrict__ mids, const float* __restrict__ mwts,
    const float* __restrict__ motif,
    const float* __restrict__ b_nb, const float* __restrict__ b_pos, const float* __restrict__ b_str,
    const float* __restrict__ W2, const float* __restrict__ b2,
    const float* __restrict__ pos, const float* __restrict__ gateq,
    const u16* __restrict__ WBg,
    float* __restrict__ out, int E, int NT)
{
  __shared__ __align__(16) u16 XB[8*64*8];       // X chunk: 8 edge-tiles x 64 lanes x 8 (8 KB)
  __shared__ __align__(16) u16 FT2[8*8*64*8];    // fused [k=256][edge=128] frag order (64 KB)
  __shared__ float woacc[4][128];                // layer-2 per-Mw partials (2 KB)

  const int t  = threadIdx.x;
  const int wv = t >> 6, l = t & 63;
  const int Mw = wv >> 1, Nw = wv & 1;           // 4 x 2 wave grid
  const int lr = l & 15, lg = l >> 4;
  const int be = blockIdx.x * 128;
  const int se = wv * 16 + lr;                   // staging edge row 0..127
  const int sko = lg * 8;                        // staging k offset

  // per-thread edge ids (row se)
  int e_r = be + se; if (e_r >= E) e_r = E - 1;
  const int hid = h_id[e_r], tid = t_id[e_r], rid = r_id[e_r];
  const float* hrow = (hid < NT) ? (ent + (size_t)hid * EMB) : ntx;
  const float* trow = (tid < NT) ? (ent + (size_t)tid * EMB) : ntx;
  const float* rrow = rel + (size_t)rid * EMB;

  const float g0 = gateq[0], g1 = gateq[1], g2 = gateq[2];

  f32x4 acc[4][4];
  short8v xp;    // next-chunk X staging value (issue-early / write-late)

  auto zacc = [&]() {
    #pragma unroll
    for (int m = 0; m < 4; ++m)
      #pragma unroll
      for (int n = 0; n < 4; ++n)
        acc[m][n] = (f32x4){0.f, 0.f, 0.f, 0.f};
  };

  // load X chunk c's slice for this thread into xp
  auto xload = [&](int c) {
    if (c < 16) {
      const float* src = ((c < 8) ? hrow : trow) + (c & 7) * 32 + sko;
      xp = pack8(*(const float4*)src, *(const float4*)(src + 4));
    } else if (c == 16) {
      float vals[8];
      #pragma unroll
      for (int j = 0; j < 8; ++j) {
        int k = sko + j;
        vals[j] = (k < 10) ? pos[(size_t)hid*10 + k]
                : (k < 20) ? pos[(size_t)tid*10 + (k - 10)] : 0.f;
      }
      short8v v;
      #pragma unroll
      for (int j = 0; j < 8; ++j) v[j] = (short)f2bf(vals[j]);
      xp = v;
    } else if (c < 25) {
      const float* src = rrow + (c - 17) * 32 + sko;
      xp = pack8(*(const float4*)src, *(const float4*)(src + 4));
    } else {  // 25, 26: motif weighted sum over 8 tokens, dims d0..d0+8
      int d0 = (c - 25) * 32 + sko;
      float s[8] = {0,0,0,0,0,0,0,0};
      #pragma unroll
      for (int j = 0; j < 8; ++j) {
        int id = mids[(size_t)e_r*8 + j];
        float wj = mwts[(size_t)e_r*8 + j];
        if (id != 0) {
          const float* mr = motif + (size_t)id*64 + d0;
          #pragma unroll
          for (int i = 0; i < 8; ++i) s[i] = fmaf(mr[i], wj, s[i]);
        }
      }
      short8v v;
      #pragma unroll
      for (int i = 0; i < 8; ++i) v[i] = (short)f2bf(s[i]);
      xp = v;
    }
  };

  // channel result -> FT2 (bf16 frag order), RMW accumulate
  auto combine = [&](const float* bias, float g, bool first) {
    #pragma unroll
    for (int m = 0; m < 4; ++m) {
      int f0 = Mw*64 + m*16 + lg*4;
      float bv0 = bias[f0+0], bv1 = bias[f0+1], bv2 = bias[f0+2], bv3 = bias[f0+3];
      int kc  = Mw*2 + ((m*4 + lg) >> 3);
      int lg2 = (m*2 + (lg >> 1)) & 3;
      #pragma unroll
      for (int n = 0; n < 4; ++n) {
        int nt = Nw*4 + n;
        int idx = ((kc*8 + nt)*64 + lg2*16 + lr)*8 + (lg & 1)*4;
        float v0 = g * fmaxf(acc[m][n][0] + bv0, 0.f);
        float v1 = g * fmaxf(acc[m][n][1] + bv1, 0.f);
        float v2 = g * fmaxf(acc[m][n][2] + bv2, 0.f);
        float v3 = g * fmaxf(acc[m][n][3] + bv3, 0.f);
        if (!first) {
          short4v o = *(short4v*)&FT2[idx];
          v0 += bf2f((u16)o[0]); v1 += bf2f((u16)o[1]);
          v2 += bf2f((u16)o[2]); v3 += bf2f((u16)o[3]);
        }
        short4v w;
        w[0] = (short)f2bf(v0); w[1] = (short)f2bf(v1);
        w[2] = (short)f2bf(v2); w[3] = (short)f2bf(v3);
        *(short4v*)&FT2[idx] = w;
      }
    }
  };

  // ===== prologue: stage X chunk 0 =====
  zacc();
  xload(0);
  *(short8v*)&XB[t * 8] = xp;
  __syncthreads();

  // ===== channel chunks: c = 0..26 (ch1: 0-15, ch2: 16, ch3: 17-26) =====
  for (int c = 0; c < 27; ++c) {
    // W fragments: direct from global (L2)
    const u16* wc = WBg + (size_t)c * 8192;
    short8v af[4];
    #pragma unroll
    for (int m = 0; m < 4; ++m)
      af[m] = *(const short8v*)&wc[((Mw*4 + m)*64 + l) * 8];
    // issue next-chunk X gather early (lands under MFMA + barrier)
    if (c < 26) xload(c + 1);
    short8v bfr[4];
    #pragma unroll
    for (int n = 0; n < 4; ++n)
      bfr[n] = *(const short8v*)&XB[((Nw*4 + n)*64 + l) * 8];
    #pragma unroll
    for (int m = 0; m < 4; ++m)
      #pragma unroll
      for (int n = 0; n < 4; ++n)
        acc[m][n] = __builtin_amdgcn_mfma_f32_16x16x32_bf16(af[m], bfr[n], acc[m][n], 0, 0, 0);
    if (c == 15)      { combine(b_nb,  g0, true);  zacc(); }
    else if (c == 16) { combine(b_pos, g1, false); zacc(); }
    __syncthreads();                    // all waves done reading XB
    if (c < 26) {
      *(short8v*)&XB[t * 8] = xp;       // write-late
      __syncthreads();                  // next chunk ready
    }
  }
  combine(b_str, g2, false);

  // ===== layer 1: acc init = qpart (b1 + q@W1_top), B = FT2, W1 kt 27..34 =====
  #pragma unroll
  for (int m = 0; m < 4; ++m) {
    int f0 = Mw*64 + m*16 + lg*4;
    f32x4 qv = { gateq[4+f0], gateq[5+f0], gateq[6+f0], gateq[7+f0] };
    #pragma unroll
    for (int n = 0; n < 4; ++n) acc[m][n] = qv;
  }
  __syncthreads();                      // FT2 fully written
  for (int c2 = 0; c2 < 8; ++c2) {
    const u16* wc = WBg + (size_t)(27 + c2) * 8192;
    short8v af[4], bfr[4];
    #pragma unroll
    for (int m = 0; m < 4; ++m)
      af[m] = *(const short8v*)&wc[((Mw*4 + m)*64 + l) * 8];
    #pragma unroll
    for (int n = 0; n < 4; ++n)
      bfr[n] = *(const short8v*)&FT2[((c2*8 + Nw*4 + n)*64 + l) * 8];
    #pragma unroll
    for (int m = 0; m < 4; ++m)
      #pragma unroll
      for (int n = 0; n < 4; ++n)
        acc[m][n] = __builtin_amdgcn_mfma_f32_16x16x32_bf16(af[m], bfr[n], acc[m][n], 0, 0, 0);
  }

  // ===== layer 2: out = relu(act) @ W2 + b2, per-wave partials =====
  {
    float w2v[4][4];
    #pragma unroll
    for (int m = 0; m < 4; ++m) {
      int f0 = Mw*64 + m*16 + lg*4;
      #pragma unroll
      for (int r2 = 0; r2 < 4; ++r2) w2v[m][r2] = W2[f0 + r2];
    }
    #pragma unroll
    for (int n = 0; n < 4; ++n) {
      float p = 0.f;
      #pragma unroll
      for (int m = 0; m < 4; ++m)
        #pragma unroll
        for (int r2 = 0; r2 < 4; ++r2)
          p = fmaf(fmaxf(acc[m][n][r2], 0.f), w2v[m][r2], p);
      p += __shfl_xor(p, 16);
      p += __shfl_xor(p, 32);
      if (lg == 0) woacc[Mw][Nw*64 + n*16 + lr] = p;
    }
  }
  __syncthreads();
  if (t < 128) {
    int e = be + t;
    if (e < E)
      out[e] = woacc[0][t] + woacc[1][t] + woacc[2][t] + woacc[3][t] + b2[0];
  }
}

extern "C" void kernel_launch(void* const* d_in, const int* in_sizes, int n_in,
                              void* d_out, int out_size, void* d_ws, size_t ws_size,
                              hipStream_t stream) {
  const int*   h_id  = (const int*)  d_in[0];
  const int*   r_id  = (const int*)  d_in[1];
  const int*   t_id  = (const int*)  d_in[2];
  const float* q     = (const float*)d_in[3];
  const float* ent   = (const float*)d_in[4];
  const float* rel   = (const float*)d_in[6];
  const float* topic = (const float*)d_in[7];
  const int*   mids  = (const int*)  d_in[8];
  const float* mwts  = (const float*)d_in[9];
  const float* ntx   = (const float*)d_in[10];
  const float* motif = (const float*)d_in[11];
  const float* W_nb  = (const float*)d_in[12];
  const float* b_nb  = (const float*)d_in[13];
  const float* W_pos = (const float*)d_in[14];
  const float* b_pos = (const float*)d_in[15];
  const float* W_str = (const float*)d_in[16];
  const float* b_str = (const float*)d_in[17];
  const float* W_g   = (const float*)d_in[18];
  const float* b_g   = (const float*)d_in[19];
  const float* W1    = (const float*)d_in[20];
  const float* b1    = (const float*)d_in[21];
  const float* W2    = (const float*)d_in[22];
  const float* b2    = (const float*)d_in[23];
  float* out = (float*)d_out;

  const int E  = in_sizes[0];
  const int NT = in_sizes[4] / EMB;   // 80000 text entities
  const int N  = in_sizes[7] / 2;     // 100000 total nodes

  float* ws    = (float*)d_ws;
  float* cnt_f = ws;
  float* cnt_r = ws + (size_t)N;
  float* a1f   = ws + (size_t)2*N;
  float* a1r   = ws + (size_t)4*N;
  float* a2f   = ws + (size_t)6*N;
  float* a2r   = ws + (size_t)8*N;
  float* pos   = ws + (size_t)10*N;   // N x 10
  float* gateq = ws + (size_t)20*N;   // [g0,g1,g2,pad, qpart(256)]
  u16*   WBg   = (u16*)(ws + (size_t)20*N + 512);  // 35 chunks x 16KB bf16 frags

  hipMemsetAsync(d_ws, 0, (size_t)10 * N * sizeof(float), stream);

  int gE = (E + 255) / 256, gN = (N + 255) / 256;
  k_scatter1<<<gE, 256, 0, stream>>>(h_id, t_id, topic, cnt_f, cnt_r, a1f, a1r, E);
  k_div1    <<<gN, 256, 0, stream>>>(topic, cnt_f, cnt_r, a1f, a1r, pos, N);
  k_scatter2<<<gE, 256, 0, stream>>>(h_id, t_id, pos, a2f, a2r, E);
  k_div2    <<<gN, 256, 0, stream>>>(cnt_f, cnt_r, a2f, a2r, pos, N);
  k_gate    <<<1, 256, 0, stream>>>(q, W_g, b_g, W1, b1, gateq);
  k_wtrans  <<<140, 256, 0, stream>>>(W_nb, W_pos, W_str, W1, (u16*)WBg);

  int gM = (E + 127) / 128;
  k_main<<<gM, 512, 0, stream>>>(h_id, r_id, t_id, ent, ntx, rel, mids, mwts, motif,
                                 b_nb, b_pos, b_str, W2, b2,
                                 pos, gateq, WBg, out, E, NT);
}